// Round 21
// baseline (112.187 us; speedup 1.0000x reference)
//
#include <hip/hip_runtime.h>
#include <math.h>

// Problem constants: B=32, F=2048, hw=49, A=1.
#define BB    32
#define FF    2048
#define HW    49
#define ROWS  (BB * FF)
#define DPAD  64
#define SPLIT 8
#define FTG   4
#define GHALF (FF / SPLIT)               // 256
#define NST   (GHALF / 32)               // 8 g-tiles of 32 rows per wave

typedef float f32x16 __attribute__((ext_vector_type(16)));
typedef _Float16 f16x8 __attribute__((ext_vector_type(8)));
typedef short s16x8 __attribute__((ext_vector_type(8)));

// exp2 via the amdgcn builtin -> single v_exp_f32, compiler-managed hazards.
__device__ inline float exp2_fast(float x) {
    return __builtin_amdgcn_exp2f(x);
}

// fp32 -> fp16 hi + fp16 lo (RNE), packed (hi<<16)|lo. Combined rel err ~2^-22.
__device__ inline unsigned f16pack(float v) {
    _Float16 h = (_Float16)v;
    _Float16 l = (_Float16)(v - (float)h);
    unsigned hb = (unsigned)__builtin_bit_cast(unsigned short, h);
    unsigned lb = (unsigned)__builtin_bit_cast(unsigned short, l);
    return (hb << 16) | lb;
}

__device__ inline void unpack8(uint4 a, uint4 b, f16x8& h, f16x8& l) {
    unsigned w[8] = {a.x, a.y, a.z, a.w, b.x, b.y, b.z, b.w};
    s16x8 hs, ls;
    #pragma unroll
    for (int i = 0; i < 8; ++i) {
        hs[i] = (short)(w[i] >> 16);
        ls[i] = (short)(w[i] & 0xFFFFu);
    }
    h = __builtin_bit_cast(f16x8, hs);
    l = __builtin_bit_cast(f16x8, ls);
}

// ---------------------------------------------------------------------------
// prep: M[j,d] = sum_e Wq[e,j] Wk[e,d] * log2(e)/7 -> Mtpk[d][j] (fp16 hi/lo)
//       u[d]   = sum_e Wv[e,d] * Wout[e]
// ---------------------------------------------------------------------------
__global__ __launch_bounds__(256) void prep_kernel(
    const float* __restrict__ Wqkv, const float* __restrict__ Wout,
    unsigned* __restrict__ Mtpk, float* __restrict__ u)
{
    __shared__ float W2[98][52];
    const int tid = threadIdx.x;
    if (blockIdx.x < 16) {
        for (int i = tid; i < 98 * 52; i += 256) {
            int e = i / 52, j = i - e * 52;
            W2[e][j] = (j < HW) ? Wqkv[e * HW + j] : 0.f;
        }
        __syncthreads();
        const int d = blockIdx.x * 4 + (tid >> 6);
        const int j = tid & 63;
        float s = 0.f;
        if (d < HW && j < HW) {
            for (int e = 0; e < HW; ++e) s = fmaf(W2[e][j], W2[49 + e][d], s);
            s *= 0.2060992915555662f;      // log2(e) / 7
        }
        Mtpk[d * 64 + j] = f16pack(s);
    } else {
        if (tid < 64) {
            float s = 0.f;
            if (tid < HW)
                for (int e = 0; e < HW; ++e)
                    s = fmaf(Wqkv[(98 + e) * HW + tid], Wout[e], s);
            u[tid] = s;
        }
    }
}

// ---------------------------------------------------------------------------
// xy: 64 rows per 128-thread block (12.5 KB LDS -> high occupancy). Load x
// via LDS bounce, build fp16 hi/lo x-frags in-register, write FRAGMENT-
// ORDERED xf panel xf[g-tile][ks][lane][8], wv = x.u, then y = x.M (3-MFMA
// hi/lo, full precision) -> y-hi fp16 panel yh[row][64].
// XCD-affinity swizzle: XCD k produces b in [4k,4k+4) (what its attn reads).
// ---------------------------------------------------------------------------
__global__ __launch_bounds__(128) void xy_kernel(
    const float* __restrict__ x, const float* __restrict__ u,
    const unsigned* __restrict__ Mtpk,
    unsigned short* __restrict__ xf, unsigned short* __restrict__ yh,
    float* __restrict__ wv)
{
    __shared__ float xsh[64 * HW];
    __shared__ float ush[64];
    const int blk = (blockIdx.x & 7) * 128 + (blockIdx.x >> 3);  // affinity map
    const int tid = threadIdx.x, lane = tid & 63, wid = tid >> 6;
    const int col = lane & 31, half = lane >> 5;
    if (tid < 64) ush[tid] = u[tid];

    {
        const float* xb = x + (size_t)blk * 64 * HW;
        for (int i = tid; i < 64 * HW; i += 128) xsh[i] = xb[i];
    }
    __syncthreads();

    const int r0 = blk * 64 + wid * 32;
    const int rloc = wid * 32 + col;
    const int row = r0 + col;
    const int tile = blk * 2 + wid;     // 32-row g-tile index

    // x row -> hi/lo frags (in-register), fragment-ordered xf write, wv
    f16x8 ah[4], al[4];
    float wp = 0.f;
    #pragma unroll
    for (int ks = 0; ks < 4; ++ks) {
        s16x8 hs, ls;
        #pragma unroll
        for (int i = 0; i < 8; ++i) {
            int d = ks * 16 + half * 8 + i;
            float t = (d < HW) ? xsh[rloc * HW + d] : 0.f;
            wp = fmaf(t, ush[d], wp);
            _Float16 h = (_Float16)t;
            _Float16 l = (_Float16)(t - (float)h);
            hs[i] = __builtin_bit_cast(short, h);
            ls[i] = __builtin_bit_cast(short, l);
        }
        ah[ks] = __builtin_bit_cast(f16x8, hs);
        al[ks] = __builtin_bit_cast(f16x8, ls);
        // fragment order: [tile][ks][lane][8] -> contiguous per-wave 1KB
        *(f16x8*)(xf + ((size_t)tile * 4 + ks) * 512 + lane * 8) = ah[ks];
    }
    wp += __shfl_xor(wp, 32);
    if (half == 0) wv[row] = wp;

    // y = x.M for this wave's 32 rows (A = x-row frags, B = Mt-row frags)
    for (int dt = 0; dt < 2; ++dt) {
        f16x8 mh[4], ml[4];
        #pragma unroll
        for (int ks = 0; ks < 4; ++ks) {
            const unsigned* mp = Mtpk + (dt * 32 + col) * 64 + ks * 16 + half * 8;
            unpack8(*(const uint4*)mp, *(const uint4*)(mp + 4), mh[ks], ml[ks]);
        }
        f32x16 acc;
        #pragma unroll
        for (int i = 0; i < 16; ++i) acc[i] = 0.f;
        #pragma unroll
        for (int ks = 0; ks < 4; ++ks) {
            acc = __builtin_amdgcn_mfma_f32_32x32x16_f16(ah[ks], ml[ks], acc, 0, 0, 0);
            acc = __builtin_amdgcn_mfma_f32_32x32x16_f16(al[ks], mh[ks], acc, 0, 0, 0);
            acc = __builtin_amdgcn_mfma_f32_32x32x16_f16(ah[ks], mh[ks], acc, 0, 0, 0);
        }
        #pragma unroll
        for (int reg = 0; reg < 16; ++reg) {
            int drow = (reg & 3) + 8 * (reg >> 2) + 4 * half;
            _Float16 hv = (_Float16)acc[reg];
            yh[(size_t)(r0 + drow) * DPAD + dt * 32 + col] =
                __builtin_bit_cast(unsigned short, hv);
        }
    }
}

// ---------------------------------------------------------------------------
// attn, barrier-free, FTG=4 high-intensity waves: each WAVE owns (b, 128
// f-cols, 256-g strip). No LDS/barriers. Each fragment-ordered A-tile load
// (2KB wave-load, local-L2 by affinity) feeds 16 MFMA + 64 exp (4
// f-subtiles) -- 4x the arithmetic intensity of round 17, cutting the L1
// stream 512->128 MB (round 20 showed traffic-per-f-col is the binding
// term). The w-quads depend only on g, so all 4 subtiles SHARE them (per-
// element overhead /4). launch_bounds(256,1): no register cap -> no spill
// lottery (rounds 12/13/16 lesson). af register-dbuf (r18 proven pattern).
// 4 waves/block share the g-strip -> L1 serves 3/4 of af reads.
// ---------------------------------------------------------------------------
__global__ __launch_bounds__(256, 1) void attn_kernel(
    const unsigned short* __restrict__ xf, const unsigned short* __restrict__ yh,
    const float* __restrict__ wv,
    float* __restrict__ partL, float* __restrict__ partA)
{
    // XCD-chunked swizzle: 1024 blocks, 128 logical per XCD -> b in [4k,4k+4).
    const int bid = blockIdx.x;
    const int L = (bid & 7) * 128 + (bid >> 3);
    const int b   = L >> 5;
    const int r31 = L & 31;
    const int fgb = r31 >> 3;     // 0..3
    const int sp  = r31 & 7;      // 0..7: SAME for all block waves

    const int tid  = threadIdx.x;
    const int lane = tid & 63;
    const int wid  = tid >> 6;
    const int col  = lane & 31;
    const int half = lane >> 5;

    const int fblk0  = fgb * 512 + wid * 128;   // wave covers 128 f-cols
    const int gstart = sp * GHALF;
    const size_t bq = (size_t)b * FF;

    // hoist y-hi fragments for 4 f-subtiles (B operand)
    f16x8 qhf[FTG][4];
    #pragma unroll
    for (int fs = 0; fs < FTG; ++fs) {
        const size_t yrow = (bq + fblk0 + fs * 32 + col) * DPAD;
        #pragma unroll
        for (int ks = 0; ks < 4; ++ks)
            qhf[fs][ks] = *(const f16x8*)(yh + yrow + ks * 16 + half * 8);
    }

    // fragment-ordered af base: tile t -> abase + t*2048 + ks*512 (shorts)
    const unsigned short* abase =
        xf + ((size_t)(b * (FF / 32) + sp * NST) * 4) * 512 + lane * 8;
    const float* wbase = wv + bq + gstart + 4 * half;

    float lsum[FTG];
    float av[FTG][4];
    #pragma unroll
    for (int fs = 0; fs < FTG; ++fs) {
        lsum[fs] = 0.f;
        #pragma unroll
        for (int j = 0; j < 4; ++j) av[fs][j] = 0.f;
    }

    f16x8 afA[4], afB[4];
    #pragma unroll
    for (int ks = 0; ks < 4; ++ks)
        afA[ks] = *(const f16x8*)(abase + (size_t)ks * 512);

    #pragma unroll
    for (int t = 0; t < NST; t += 2) {
        // prefetch tile t+1 into B
        #pragma unroll
        for (int ks = 0; ks < 4; ++ks)
            afB[ks] = *(const f16x8*)(abase + (size_t)(t + 1) * 2048 + ks * 512);

        // compute tile t from A (w-quads shared across the 4 f-subtiles)
        {
            float4 wq0 = *(const float4*)(wbase + t * 32);
            float4 wq1 = *(const float4*)(wbase + t * 32 + 8);
            float4 wq2 = *(const float4*)(wbase + t * 32 + 16);
            float4 wq3 = *(const float4*)(wbase + t * 32 + 24);
            #pragma unroll
            for (int fs = 0; fs < FTG; ++fs) {
                f32x16 acc;
                #pragma unroll
                for (int i = 0; i < 16; ++i) acc[i] = 0.f;
                #pragma unroll
                for (int ks = 0; ks < 4; ++ks)
                    acc = __builtin_amdgcn_mfma_f32_32x32x16_f16(afA[ks], qhf[fs][ks], acc, 0, 0, 0);
                // D row g = (reg&3) + 8*(reg>>2) + 4*half; reg = q*4+j
                const float4 wqs[4] = {wq0, wq1, wq2, wq3};
                #pragma unroll
                for (int q = 0; q < 4; ++q) {
                    float p0 = exp2_fast(acc[q * 4 + 0]);
                    float p1 = exp2_fast(acc[q * 4 + 1]);
                    float p2 = exp2_fast(acc[q * 4 + 2]);
                    float p3 = exp2_fast(acc[q * 4 + 3]);
                    lsum[fs] += ((p0 + p1) + (p2 + p3));
                    av[fs][0] = fmaf(p0, wqs[q].x, av[fs][0]);
                    av[fs][1] = fmaf(p1, wqs[q].y, av[fs][1]);
                    av[fs][2] = fmaf(p2, wqs[q].z, av[fs][2]);
                    av[fs][3] = fmaf(p3, wqs[q].w, av[fs][3]);
                }
            }
        }

        // prefetch tile t+2 into A
        if (t + 2 < NST) {
            #pragma unroll
            for (int ks = 0; ks < 4; ++ks)
                afA[ks] = *(const f16x8*)(abase + (size_t)(t + 2) * 2048 + ks * 512);
        }

        // compute tile t+1 from B
        {
            float4 wq0 = *(const float4*)(wbase + (t + 1) * 32);
            float4 wq1 = *(const float4*)(wbase + (t + 1) * 32 + 8);
            float4 wq2 = *(const float4*)(wbase + (t + 1) * 32 + 16);
            float4 wq3 = *(const float4*)(wbase + (t + 1) * 32 + 24);
            #pragma unroll
            for (int fs = 0; fs < FTG; ++fs) {
                f32x16 acc;
                #pragma unroll
                for (int i = 0; i < 16; ++i) acc[i] = 0.f;
                #pragma unroll
                for (int ks = 0; ks < 4; ++ks)
                    acc = __builtin_amdgcn_mfma_f32_32x32x16_f16(afB[ks], qhf[fs][ks], acc, 0, 0, 0);
                const float4 wqs[4] = {wq0, wq1, wq2, wq3};
                #pragma unroll
                for (int q = 0; q < 4; ++q) {
                    float p0 = exp2_fast(acc[q * 4 + 0]);
                    float p1 = exp2_fast(acc[q * 4 + 1]);
                    float p2 = exp2_fast(acc[q * 4 + 2]);
                    float p3 = exp2_fast(acc[q * 4 + 3]);
                    lsum[fs] += ((p0 + p1) + (p2 + p3));
                    av[fs][0] = fmaf(p0, wqs[q].x, av[fs][0]);
                    av[fs][1] = fmaf(p1, wqs[q].y, av[fs][1]);
                    av[fs][2] = fmaf(p2, wqs[q].z, av[fs][2]);
                    av[fs][3] = fmaf(p3, wqs[q].w, av[fs][3]);
                }
            }
        }
    }

    #pragma unroll
    for (int fs = 0; fs < FTG; ++fs) {
        float l = lsum[fs];
        float a = (av[fs][0] + av[fs][1]) + (av[fs][2] + av[fs][3]);
        l += __shfl_xor(l, 32);
        a += __shfl_xor(a, 32);
        if (half == 0) {
            size_t o = ((size_t)sp * BB + b) * FF + fblk0 + fs * 32 + col;
            partL[o] = l;
            partA[o] = a;
        }
    }
}

// ---------------------------------------------------------------------------
// bn: combine split partials, BatchNorm over batch per channel f.
// ---------------------------------------------------------------------------
__global__ __launch_bounds__(64) void bn_kernel(
    const float* __restrict__ partL, const float* __restrict__ partA,
    const float* __restrict__ gamma, const float* __restrict__ beta,
    float* __restrict__ out)
{
    const int f = blockIdx.x * 64 + threadIdx.x;
    float v[BB];
    float mean = 0.f;
    #pragma unroll
    for (int b = 0; b < BB; ++b) {
        float l = 0.f, a = 0.f;
        #pragma unroll
        for (int s = 0; s < SPLIT; ++s) {
            l += partL[((size_t)s * BB + b) * FF + f];
            a += partA[((size_t)s * BB + b) * FF + f];
        }
        v[b] = a / l;
        mean += v[b];
    }
    mean *= (1.f / BB);
    float var = 0.f;
    #pragma unroll
    for (int b = 0; b < BB; ++b) {
        float d = v[b] - mean;
        var = fmaf(d, d, var);
    }
    var *= (1.f / BB);
    const float inv = rsqrtf(var + 1e-5f);
    const float g = gamma[f], be = beta[f];
    #pragma unroll
    for (int b = 0; b < BB; ++b)
        out[((size_t)b << 11) + f] = (v[b] - mean) * inv * g + be;
}

// ---------------------------------------------------------------------------
extern "C" void kernel_launch(void* const* d_in, const int* in_sizes, int n_in,
                              void* d_out, int out_size, void* d_ws, size_t ws_size,
                              hipStream_t stream)
{
    const float* x     = (const float*)d_in[0];
    const float* Wqkv  = (const float*)d_in[1];
    const float* Wout  = (const float*)d_in[2];
    // d_in[3] = b_out: cancels exactly under BatchNorm mean subtraction.
    const float* gamma = (const float*)d_in[4];
    const float* beta  = (const float*)d_in[5];

    char* wsb = (char*)d_ws;
    const size_t PANEL = (size_t)ROWS * DPAD * sizeof(unsigned short);  // 8 MB
    unsigned short* xf = (unsigned short*)(wsb);        // fragment-ordered
    unsigned short* yh = (unsigned short*)(wsb + PANEL);
    float*          wv = (float*)(wsb + 2 * PANEL);                     // 256 KB
    unsigned*     Mtpk = (unsigned*)(wsb + 2 * PANEL + 262144);         // 16 KB
    float*           u = (float*)(wsb + 2 * PANEL + 262144 + 16384);
    float*       partL = (float*)(wsb + 2 * PANEL + 262144 + 17408);
    float*       partA = partL + (size_t)SPLIT * BB * FF;
    // total ~= 22.3 MiB

    prep_kernel<<<dim3(17), dim3(256), 0, stream>>>(Wqkv, Wout, Mtpk, u);

    xy_kernel<<<dim3(ROWS / 64), dim3(128), 0, stream>>>(
        x, u, Mtpk, xf, yh, wv);

    attn_kernel<<<dim3(BB * 4 * SPLIT), dim3(256), 0, stream>>>(
        xf, yh, wv, partL, partA);

    bn_kernel<<<dim3(FF / 64), dim3(64), 0, stream>>>(
        partL, partA, gamma, beta, (float*)d_out);
}

// Round 22
// 89.678 us; speedup vs baseline: 1.2510x; 1.2510x over previous
//
#include <hip/hip_runtime.h>
#include <math.h>

// Problem constants: B=32, F=2048, hw=49, A=1.
#define BB    32
#define FF    2048
#define HW    49
#define ROWS  (BB * FF)
#define DPAD  64
#define SPLIT 4
#define GHALF (FF / SPLIT)               // 512
#define NST   (GHALF / 32)               // 16 g-tiles of 32 rows

typedef float f32x16 __attribute__((ext_vector_type(16)));
typedef _Float16 f16x8 __attribute__((ext_vector_type(8)));
typedef short s16x8 __attribute__((ext_vector_type(8)));

// exp2 via the amdgcn builtin -> single v_exp_f32, compiler-managed hazards.
__device__ inline float exp2_fast(float x) {
    return __builtin_amdgcn_exp2f(x);
}

// fp32 -> fp16 hi + fp16 lo (RNE), packed (hi<<16)|lo. Combined rel err ~2^-22.
__device__ inline unsigned f16pack(float v) {
    _Float16 h = (_Float16)v;
    _Float16 l = (_Float16)(v - (float)h);
    unsigned hb = (unsigned)__builtin_bit_cast(unsigned short, h);
    unsigned lb = (unsigned)__builtin_bit_cast(unsigned short, l);
    return (hb << 16) | lb;
}

__device__ inline void unpack8(uint4 a, uint4 b, f16x8& h, f16x8& l) {
    unsigned w[8] = {a.x, a.y, a.z, a.w, b.x, b.y, b.z, b.w};
    s16x8 hs, ls;
    #pragma unroll
    for (int i = 0; i < 8; ++i) {
        hs[i] = (short)(w[i] >> 16);
        ls[i] = (short)(w[i] & 0xFFFFu);
    }
    h = __builtin_bit_cast(f16x8, hs);
    l = __builtin_bit_cast(f16x8, ls);
}

// ---------------------------------------------------------------------------
// prep: M[j,d] = sum_e Wq[e,j] Wk[e,d] * log2(e)/7 -> Mtpk[d][j] (fp16 hi/lo)
//       u[d]   = sum_e Wv[e,d] * Wout[e]
// ---------------------------------------------------------------------------
__global__ __launch_bounds__(256) void prep_kernel(
    const float* __restrict__ Wqkv, const float* __restrict__ Wout,
    unsigned* __restrict__ Mtpk, float* __restrict__ u)
{
    __shared__ float W2[98][52];
    const int tid = threadIdx.x;
    if (blockIdx.x < 16) {
        for (int i = tid; i < 98 * 52; i += 256) {
            int e = i / 52, j = i - e * 52;
            W2[e][j] = (j < HW) ? Wqkv[e * HW + j] : 0.f;
        }
        __syncthreads();
        const int d = blockIdx.x * 4 + (tid >> 6);
        const int j = tid & 63;
        float s = 0.f;
        if (d < HW && j < HW) {
            for (int e = 0; e < HW; ++e) s = fmaf(W2[e][j], W2[49 + e][d], s);
            s *= 0.2060992915555662f;      // log2(e) / 7
        }
        Mtpk[d * 64 + j] = f16pack(s);
    } else {
        if (tid < 64) {
            float s = 0.f;
            if (tid < HW)
                for (int e = 0; e < HW; ++e)
                    s = fmaf(Wqkv[(98 + e) * HW + tid], Wout[e], s);
            u[tid] = s;
        }
    }
}

// ---------------------------------------------------------------------------
// xy: 64 rows per 128-thread block (12.5 KB LDS -> high occupancy). Load x
// via LDS bounce, build fp16 hi/lo x-frags in-register, write FRAGMENT-
// ORDERED xf panel xf[g-tile][ks][lane][8], wv = x.u, then y = x.M (3-MFMA
// hi/lo, full precision) -> y-hi fp16 panel yh[row][64].
// XCD-affinity swizzle: XCD k produces b in [4k,4k+4) (what its attn reads).
// ---------------------------------------------------------------------------
__global__ __launch_bounds__(128) void xy_kernel(
    const float* __restrict__ x, const float* __restrict__ u,
    const unsigned* __restrict__ Mtpk,
    unsigned short* __restrict__ xf, unsigned short* __restrict__ yh,
    float* __restrict__ wv)
{
    __shared__ float xsh[64 * HW];
    __shared__ float ush[64];
    const int blk = (blockIdx.x & 7) * 128 + (blockIdx.x >> 3);  // affinity map
    const int tid = threadIdx.x, lane = tid & 63, wid = tid >> 6;
    const int col = lane & 31, half = lane >> 5;
    if (tid < 64) ush[tid] = u[tid];

    {
        const float* xb = x + (size_t)blk * 64 * HW;
        for (int i = tid; i < 64 * HW; i += 128) xsh[i] = xb[i];
    }
    __syncthreads();

    const int r0 = blk * 64 + wid * 32;
    const int rloc = wid * 32 + col;
    const int row = r0 + col;
    const int tile = blk * 2 + wid;     // 32-row g-tile index

    // x row -> hi/lo frags (in-register), fragment-ordered xf write, wv
    f16x8 ah[4], al[4];
    float wp = 0.f;
    #pragma unroll
    for (int ks = 0; ks < 4; ++ks) {
        s16x8 hs, ls;
        #pragma unroll
        for (int i = 0; i < 8; ++i) {
            int d = ks * 16 + half * 8 + i;
            float t = (d < HW) ? xsh[rloc * HW + d] : 0.f;
            wp = fmaf(t, ush[d], wp);
            _Float16 h = (_Float16)t;
            _Float16 l = (_Float16)(t - (float)h);
            hs[i] = __builtin_bit_cast(short, h);
            ls[i] = __builtin_bit_cast(short, l);
        }
        ah[ks] = __builtin_bit_cast(f16x8, hs);
        al[ks] = __builtin_bit_cast(f16x8, ls);
        // fragment order: [tile][ks][lane][8] -> contiguous per-wave 1KB
        *(f16x8*)(xf + ((size_t)tile * 4 + ks) * 512 + lane * 8) = ah[ks];
    }
    wp += __shfl_xor(wp, 32);
    if (half == 0) wv[row] = wp;

    // y = x.M for this wave's 32 rows (A = x-row frags, B = Mt-row frags)
    for (int dt = 0; dt < 2; ++dt) {
        f16x8 mh[4], ml[4];
        #pragma unroll
        for (int ks = 0; ks < 4; ++ks) {
            const unsigned* mp = Mtpk + (dt * 32 + col) * 64 + ks * 16 + half * 8;
            unpack8(*(const uint4*)mp, *(const uint4*)(mp + 4), mh[ks], ml[ks]);
        }
        f32x16 acc;
        #pragma unroll
        for (int i = 0; i < 16; ++i) acc[i] = 0.f;
        #pragma unroll
        for (int ks = 0; ks < 4; ++ks) {
            acc = __builtin_amdgcn_mfma_f32_32x32x16_f16(ah[ks], ml[ks], acc, 0, 0, 0);
            acc = __builtin_amdgcn_mfma_f32_32x32x16_f16(al[ks], mh[ks], acc, 0, 0, 0);
            acc = __builtin_amdgcn_mfma_f32_32x32x16_f16(ah[ks], mh[ks], acc, 0, 0, 0);
        }
        #pragma unroll
        for (int reg = 0; reg < 16; ++reg) {
            int drow = (reg & 3) + 8 * (reg >> 2) + 4 * half;
            _Float16 hv = (_Float16)acc[reg];
            yh[(size_t)(r0 + drow) * DPAD + dt * 32 + col] =
                __builtin_bit_cast(unsigned short, hv);
        }
    }
}

// ---------------------------------------------------------------------------
// attn: round-17 kernel VERBATIM except launch_bounds(256,4) -> (256,5).
// Single-knob residency test: 5 blocks/CU = 20 waves/CU (62% cap) vs r17's
// 31% measured, 2x the outstanding loads per SIMD. VGPR cap 102 >= natural
// ~80 -> no spill expected (tripwire: WRITE_SIZE must stay ~2 MB).
// Barrier-free, triple-buffer reg prefetch, fragment-ordered xf loads,
// 4 waves/block share the g-strip.
// ---------------------------------------------------------------------------
__global__ __launch_bounds__(256, 5) void attn_kernel(
    const unsigned short* __restrict__ xf, const unsigned short* __restrict__ yh,
    const float* __restrict__ wv,
    float* __restrict__ partL, float* __restrict__ partA)
{
    // XCD-chunked swizzle: 2048 blocks, 256 logical per XCD -> b in [4k,4k+4).
    const int bid = blockIdx.x;
    const int L = (bid & 7) * 256 + (bid >> 3);
    const int b   = L >> 6;
    const int r63 = L & 63;

    const int tid  = threadIdx.x;
    const int lane = tid & 63;
    const int wid  = tid >> 6;
    const int col  = lane & 31;
    const int half = lane >> 5;

    const int sp  = r63 >> 4;                 // 0..3: SAME for all block waves
    const int ftg = (r63 & 15) * 4 + wid;     // 0..63
    const int fblk0  = ftg * 32;
    const int gstart = sp * GHALF;
    const size_t bq = (size_t)b * FF;

    // hoist y-hi fragments (B operand, col = fblk0+col)
    f16x8 qhf[4];
    {
        const size_t yrow = (bq + fblk0 + col) * DPAD;
        #pragma unroll
        for (int ks = 0; ks < 4; ++ks)
            qhf[ks] = *(const f16x8*)(yh + yrow + ks * 16 + half * 8);
    }

    // fragment-ordered af base: tile t -> abase + t*2048 + ks*512 (shorts)
    const unsigned short* abase =
        xf + ((size_t)(b * (FF / 32) + sp * NST) * 4) * 512 + lane * 8;
    const float* wbase = wv + bq + gstart + 4 * half;

    float lsum = 0.f;
    float a0 = 0.f, a1 = 0.f, a2 = 0.f, a3 = 0.f;

    f16x8 af[3][4];
    #pragma unroll
    for (int ks = 0; ks < 4; ++ks)
        af[0][ks] = *(const f16x8*)(abase + (size_t)ks * 512);
    #pragma unroll
    for (int ks = 0; ks < 4; ++ks)
        af[1][ks] = *(const f16x8*)(abase + (size_t)2048 + ks * 512);

    #pragma unroll
    for (int t = 0; t < NST; ++t) {
        // prefetch t+2 (2 tiles ahead; index (t+2)%3 is compile-time)
        if (t + 2 < NST) {
            #pragma unroll
            for (int ks = 0; ks < 4; ++ks)
                af[(t + 2) % 3][ks] =
                    *(const f16x8*)(abase + (size_t)(t + 2) * 2048 + ks * 512);
        }

        // compute tile t from af[t%3]
        f32x16 acc;
        #pragma unroll
        for (int i = 0; i < 16; ++i) acc[i] = 0.f;
        #pragma unroll
        for (int ks = 0; ks < 4; ++ks)
            acc = __builtin_amdgcn_mfma_f32_32x32x16_f16(af[t % 3][ks], qhf[ks],
                                                         acc, 0, 0, 0);
        // D row g = (reg&3) + 8*(reg>>2) + 4*half; reg = q*4+j -> g = j+8q+4half
        const float* wpb = wbase + t * 32;
        #pragma unroll
        for (int q = 0; q < 4; ++q) {
            float4 w4 = *(const float4*)(wpb + q * 8);
            float p0 = exp2_fast(acc[q * 4 + 0]);
            float p1 = exp2_fast(acc[q * 4 + 1]);
            float p2 = exp2_fast(acc[q * 4 + 2]);
            float p3 = exp2_fast(acc[q * 4 + 3]);
            lsum += ((p0 + p1) + (p2 + p3));
            a0 = fmaf(p0, w4.x, a0);
            a1 = fmaf(p1, w4.y, a1);
            a2 = fmaf(p2, w4.z, a2);
            a3 = fmaf(p3, w4.w, a3);
        }
    }

    float asum = (a0 + a1) + (a2 + a3);
    lsum += __shfl_xor(lsum, 32);
    asum += __shfl_xor(asum, 32);
    if (half == 0) {
        size_t o = ((size_t)sp * BB + b) * FF + fblk0 + col;
        partL[o] = lsum;
        partA[o] = asum;
    }
}

// ---------------------------------------------------------------------------
// bn: combine split partials, BatchNorm over batch per channel f.
// ---------------------------------------------------------------------------
__global__ __launch_bounds__(64) void bn_kernel(
    const float* __restrict__ partL, const float* __restrict__ partA,
    const float* __restrict__ gamma, const float* __restrict__ beta,
    float* __restrict__ out)
{
    const int f = blockIdx.x * 64 + threadIdx.x;
    float v[BB];
    float mean = 0.f;
    #pragma unroll
    for (int b = 0; b < BB; ++b) {
        float l = 0.f, a = 0.f;
        #pragma unroll
        for (int s = 0; s < SPLIT; ++s) {
            l += partL[((size_t)s * BB + b) * FF + f];
            a += partA[((size_t)s * BB + b) * FF + f];
        }
        v[b] = a / l;
        mean += v[b];
    }
    mean *= (1.f / BB);
    float var = 0.f;
    #pragma unroll
    for (int b = 0; b < BB; ++b) {
        float d = v[b] - mean;
        var = fmaf(d, d, var);
    }
    var *= (1.f / BB);
    const float inv = rsqrtf(var + 1e-5f);
    const float g = gamma[f], be = beta[f];
    #pragma unroll
    for (int b = 0; b < BB; ++b)
        out[((size_t)b << 11) + f] = (v[b] - mean) * inv * g + be;
}

// ---------------------------------------------------------------------------
extern "C" void kernel_launch(void* const* d_in, const int* in_sizes, int n_in,
                              void* d_out, int out_size, void* d_ws, size_t ws_size,
                              hipStream_t stream)
{
    const float* x     = (const float*)d_in[0];
    const float* Wqkv  = (const float*)d_in[1];
    const float* Wout  = (const float*)d_in[2];
    // d_in[3] = b_out: cancels exactly under BatchNorm mean subtraction.
    const float* gamma = (const float*)d_in[4];
    const float* beta  = (const float*)d_in[5];

    char* wsb = (char*)d_ws;
    const size_t PANEL = (size_t)ROWS * DPAD * sizeof(unsigned short);  // 8 MB
    unsigned short* xf = (unsigned short*)(wsb);        // fragment-ordered
    unsigned short* yh = (unsigned short*)(wsb + PANEL);
    float*          wv = (float*)(wsb + 2 * PANEL);                     // 256 KB
    unsigned*     Mtpk = (unsigned*)(wsb + 2 * PANEL + 262144);         // 16 KB
    float*           u = (float*)(wsb + 2 * PANEL + 262144 + 16384);
    float*       partL = (float*)(wsb + 2 * PANEL + 262144 + 17408);
    float*       partA = partL + (size_t)SPLIT * BB * FF;
    // total ~= 18.3 MiB

    prep_kernel<<<dim3(17), dim3(256), 0, stream>>>(Wqkv, Wout, Mtpk, u);

    xy_kernel<<<dim3(ROWS / 64), dim3(128), 0, stream>>>(
        x, u, Mtpk, xf, yh, wv);

    attn_kernel<<<dim3(BB * 64), dim3(256), 0, stream>>>(
        xf, yh, wv, partL, partA);

    bn_kernel<<<dim3(FF / 64), dim3(64), 0, stream>>>(
        partL, partA, gamma, beta, (float*)d_out);
}

// Round 23
// 66.745 us; speedup vs baseline: 1.6808x; 1.3436x over previous
//
#include <hip/hip_runtime.h>
#include <math.h>

// Problem constants: B=32, F=2048, hw=49, A=1.
#define BB    32
#define FF    2048
#define HW    49
#define ROWS  (BB * FF)
#define DPAD  64
#define SPLIT 2
#define GHALF (FF / SPLIT)               // 1024
#define NST   (GHALF / 32)               // 32 g-tiles of 32 rows

typedef float f32x16 __attribute__((ext_vector_type(16)));
typedef _Float16 f16x8 __attribute__((ext_vector_type(8)));
typedef short s16x8 __attribute__((ext_vector_type(8)));

// exp2 via the amdgcn builtin -> single v_exp_f32, compiler-managed hazards.
__device__ inline float exp2_fast(float x) {
    return __builtin_amdgcn_exp2f(x);
}

// fp32 -> fp16 hi + fp16 lo (RNE), packed (hi<<16)|lo. Combined rel err ~2^-22.
__device__ inline unsigned f16pack(float v) {
    _Float16 h = (_Float16)v;
    _Float16 l = (_Float16)(v - (float)h);
    unsigned hb = (unsigned)__builtin_bit_cast(unsigned short, h);
    unsigned lb = (unsigned)__builtin_bit_cast(unsigned short, l);
    return (hb << 16) | lb;
}

__device__ inline void unpack8(uint4 a, uint4 b, f16x8& h, f16x8& l) {
    unsigned w[8] = {a.x, a.y, a.z, a.w, b.x, b.y, b.z, b.w};
    s16x8 hs, ls;
    #pragma unroll
    for (int i = 0; i < 8; ++i) {
        hs[i] = (short)(w[i] >> 16);
        ls[i] = (short)(w[i] & 0xFFFFu);
    }
    h = __builtin_bit_cast(f16x8, hs);
    l = __builtin_bit_cast(f16x8, ls);
}

// ---------------------------------------------------------------------------
// prep: M[j,d] = sum_e Wq[e,j] Wk[e,d] * log2(e)/7 -> Mtpk[d][j] (fp16 hi/lo)
//       u[d]   = sum_e Wv[e,d] * Wout[e]
// ---------------------------------------------------------------------------
__global__ __launch_bounds__(256) void prep_kernel(
    const float* __restrict__ Wqkv, const float* __restrict__ Wout,
    unsigned* __restrict__ Mtpk, float* __restrict__ u)
{
    __shared__ float W2[98][52];
    const int tid = threadIdx.x;
    if (blockIdx.x < 16) {
        for (int i = tid; i < 98 * 52; i += 256) {
            int e = i / 52, j = i - e * 52;
            W2[e][j] = (j < HW) ? Wqkv[e * HW + j] : 0.f;
        }
        __syncthreads();
        const int d = blockIdx.x * 4 + (tid >> 6);
        const int j = tid & 63;
        float s = 0.f;
        if (d < HW && j < HW) {
            for (int e = 0; e < HW; ++e) s = fmaf(W2[e][j], W2[49 + e][d], s);
            s *= 0.2060992915555662f;      // log2(e) / 7
        }
        Mtpk[d * 64 + j] = f16pack(s);
    } else {
        if (tid < 64) {
            float s = 0.f;
            if (tid < HW)
                for (int e = 0; e < HW; ++e)
                    s = fmaf(Wqkv[(98 + e) * HW + tid], Wout[e], s);
            u[tid] = s;
        }
    }
}

// ---------------------------------------------------------------------------
// xy: 64 rows per 128-thread block. Load x via LDS bounce, build fp16 hi/lo
// x-frags in-register, write FRAGMENT-ORDERED xf panel xf[g-tile][ks][lane][8],
// wv = x.u, then y = x.M (3-MFMA hi/lo, full precision) -> yh[row][64].
// XCD-affinity swizzle: XCD k produces b in [4k,4k+4) (what its attn reads).
// ---------------------------------------------------------------------------
__global__ __launch_bounds__(128) void xy_kernel(
    const float* __restrict__ x, const float* __restrict__ u,
    const unsigned* __restrict__ Mtpk,
    unsigned short* __restrict__ xf, unsigned short* __restrict__ yh,
    float* __restrict__ wv)
{
    __shared__ float xsh[64 * HW];
    __shared__ float ush[64];
    const int blk = (blockIdx.x & 7) * 128 + (blockIdx.x >> 3);  // affinity map
    const int tid = threadIdx.x, lane = tid & 63, wid = tid >> 6;
    const int col = lane & 31, half = lane >> 5;
    if (tid < 64) ush[tid] = u[tid];

    {
        const float* xb = x + (size_t)blk * 64 * HW;
        for (int i = tid; i < 64 * HW; i += 128) xsh[i] = xb[i];
    }
    __syncthreads();

    const int r0 = blk * 64 + wid * 32;
    const int rloc = wid * 32 + col;
    const int row = r0 + col;
    const int tile = blk * 2 + wid;     // 32-row g-tile index

    // x row -> hi/lo frags (in-register), fragment-ordered xf write, wv
    f16x8 ah[4], al[4];
    float wp = 0.f;
    #pragma unroll
    for (int ks = 0; ks < 4; ++ks) {
        s16x8 hs, ls;
        #pragma unroll
        for (int i = 0; i < 8; ++i) {
            int d = ks * 16 + half * 8 + i;
            float t = (d < HW) ? xsh[rloc * HW + d] : 0.f;
            wp = fmaf(t, ush[d], wp);
            _Float16 h = (_Float16)t;
            _Float16 l = (_Float16)(t - (float)h);
            hs[i] = __builtin_bit_cast(short, h);
            ls[i] = __builtin_bit_cast(short, l);
        }
        ah[ks] = __builtin_bit_cast(f16x8, hs);
        al[ks] = __builtin_bit_cast(f16x8, ls);
        // fragment order: [tile][ks][lane][8] -> contiguous per-wave 1KB
        *(f16x8*)(xf + ((size_t)tile * 4 + ks) * 512 + lane * 8) = ah[ks];
    }
    wp += __shfl_xor(wp, 32);
    if (half == 0) wv[row] = wp;

    // y = x.M for this wave's 32 rows (A = x-row frags, B = Mt-row frags)
    for (int dt = 0; dt < 2; ++dt) {
        f16x8 mh[4], ml[4];
        #pragma unroll
        for (int ks = 0; ks < 4; ++ks) {
            const unsigned* mp = Mtpk + (dt * 32 + col) * 64 + ks * 16 + half * 8;
            unpack8(*(const uint4*)mp, *(const uint4*)(mp + 4), mh[ks], ml[ks]);
        }
        f32x16 acc;
        #pragma unroll
        for (int i = 0; i < 16; ++i) acc[i] = 0.f;
        #pragma unroll
        for (int ks = 0; ks < 4; ++ks) {
            acc = __builtin_amdgcn_mfma_f32_32x32x16_f16(ah[ks], ml[ks], acc, 0, 0, 0);
            acc = __builtin_amdgcn_mfma_f32_32x32x16_f16(al[ks], mh[ks], acc, 0, 0, 0);
            acc = __builtin_amdgcn_mfma_f32_32x32x16_f16(ah[ks], mh[ks], acc, 0, 0, 0);
        }
        #pragma unroll
        for (int reg = 0; reg < 16; ++reg) {
            int drow = (reg & 3) + 8 * (reg >> 2) + 4 * half;
            _Float16 hv = (_Float16)acc[reg];
            yh[(size_t)(r0 + drow) * DPAD + dt * 32 + col] =
                __builtin_bit_cast(unsigned short, hv);
        }
    }
}

// ---------------------------------------------------------------------------
// attn: round-17 kernel with SPLIT 4->2 (the only change besides a 2-way
// lsum split). Each wave now runs 32 tiles over a 1024-g strip: per-wave
// prologue (cold y-frag load + af pipe fill + tail/reduce/store) amortizes
// 2x better, and total wave count halves. Grid 1024 = 4 blocks/CU at the
// proven (256,4) shape (VGPR ~64, no spill). Barrier-free, triple-buffer
// reg prefetch, fragment-ordered xf loads, 4 waves/block share the g-strip.
// ---------------------------------------------------------------------------
__global__ __launch_bounds__(256, 4) void attn_kernel(
    const unsigned short* __restrict__ xf, const unsigned short* __restrict__ yh,
    const float* __restrict__ wv,
    float* __restrict__ partL, float* __restrict__ partA)
{
    // XCD-chunked swizzle: 1024 blocks, 128 logical per XCD -> b in [4k,4k+4).
    const int bid = blockIdx.x;
    const int L = (bid & 7) * 128 + (bid >> 3);
    const int b   = L >> 5;
    const int r31 = L & 31;

    const int tid  = threadIdx.x;
    const int lane = tid & 63;
    const int wid  = tid >> 6;
    const int col  = lane & 31;
    const int half = lane >> 5;

    const int sp  = r31 >> 4;                 // 0..1: SAME for all block waves
    const int ftg = (r31 & 15) * 4 + wid;     // 0..63
    const int fblk0  = ftg * 32;
    const int gstart = sp * GHALF;
    const size_t bq = (size_t)b * FF;

    // hoist y-hi fragments (B operand, col = fblk0+col)
    f16x8 qhf[4];
    {
        const size_t yrow = (bq + fblk0 + col) * DPAD;
        #pragma unroll
        for (int ks = 0; ks < 4; ++ks)
            qhf[ks] = *(const f16x8*)(yh + yrow + ks * 16 + half * 8);
    }

    // fragment-ordered af base: tile t -> abase + t*2048 + ks*512 (shorts)
    const unsigned short* abase =
        xf + ((size_t)(b * (FF / 32) + sp * NST) * 4) * 512 + lane * 8;
    const float* wbase = wv + bq + gstart + 4 * half;

    float l0 = 0.f, l1 = 0.f;
    float a0 = 0.f, a1 = 0.f, a2 = 0.f, a3 = 0.f;

    f16x8 af[3][4];
    #pragma unroll
    for (int ks = 0; ks < 4; ++ks)
        af[0][ks] = *(const f16x8*)(abase + (size_t)ks * 512);
    #pragma unroll
    for (int ks = 0; ks < 4; ++ks)
        af[1][ks] = *(const f16x8*)(abase + (size_t)2048 + ks * 512);

    #pragma unroll
    for (int t = 0; t < NST; ++t) {
        // prefetch t+2 (2 tiles ahead; index (t+2)%3 is compile-time)
        if (t + 2 < NST) {
            #pragma unroll
            for (int ks = 0; ks < 4; ++ks)
                af[(t + 2) % 3][ks] =
                    *(const f16x8*)(abase + (size_t)(t + 2) * 2048 + ks * 512);
        }

        // compute tile t from af[t%3]
        f32x16 acc;
        #pragma unroll
        for (int i = 0; i < 16; ++i) acc[i] = 0.f;
        #pragma unroll
        for (int ks = 0; ks < 4; ++ks)
            acc = __builtin_amdgcn_mfma_f32_32x32x16_f16(af[t % 3][ks], qhf[ks],
                                                         acc, 0, 0, 0);
        // D row g = (reg&3) + 8*(reg>>2) + 4*half; reg = q*4+j -> g = j+8q+4half
        const float* wpb = wbase + t * 32;
        #pragma unroll
        for (int q = 0; q < 4; ++q) {
            float4 w4 = *(const float4*)(wpb + q * 8);
            float p0 = exp2_fast(acc[q * 4 + 0]);
            float p1 = exp2_fast(acc[q * 4 + 1]);
            float p2 = exp2_fast(acc[q * 4 + 2]);
            float p3 = exp2_fast(acc[q * 4 + 3]);
            if (q & 1) l1 += ((p0 + p1) + (p2 + p3));
            else       l0 += ((p0 + p1) + (p2 + p3));
            a0 = fmaf(p0, w4.x, a0);
            a1 = fmaf(p1, w4.y, a1);
            a2 = fmaf(p2, w4.z, a2);
            a3 = fmaf(p3, w4.w, a3);
        }
    }

    float lsum = l0 + l1;
    float asum = (a0 + a1) + (a2 + a3);
    lsum += __shfl_xor(lsum, 32);
    asum += __shfl_xor(asum, 32);
    if (half == 0) {
        size_t o = ((size_t)sp * BB + b) * FF + fblk0 + col;
        partL[o] = lsum;
        partA[o] = asum;
    }
}

// ---------------------------------------------------------------------------
// bn: combine split partials, BatchNorm over batch per channel f.
// ---------------------------------------------------------------------------
__global__ __launch_bounds__(64) void bn_kernel(
    const float* __restrict__ partL, const float* __restrict__ partA,
    const float* __restrict__ gamma, const float* __restrict__ beta,
    float* __restrict__ out)
{
    const int f = blockIdx.x * 64 + threadIdx.x;
    float v[BB];
    float mean = 0.f;
    #pragma unroll
    for (int b = 0; b < BB; ++b) {
        float l = 0.f, a = 0.f;
        #pragma unroll
        for (int s = 0; s < SPLIT; ++s) {
            l += partL[((size_t)s * BB + b) * FF + f];
            a += partA[((size_t)s * BB + b) * FF + f];
        }
        v[b] = a / l;
        mean += v[b];
    }
    mean *= (1.f / BB);
    float var = 0.f;
    #pragma unroll
    for (int b = 0; b < BB; ++b) {
        float d = v[b] - mean;
        var = fmaf(d, d, var);
    }
    var *= (1.f / BB);
    const float inv = rsqrtf(var + 1e-5f);
    const float g = gamma[f], be = beta[f];
    #pragma unroll
    for (int b = 0; b < BB; ++b)
        out[((size_t)b << 11) + f] = (v[b] - mean) * inv * g + be;
}

// ---------------------------------------------------------------------------
extern "C" void kernel_launch(void* const* d_in, const int* in_sizes, int n_in,
                              void* d_out, int out_size, void* d_ws, size_t ws_size,
                              hipStream_t stream)
{
    const float* x     = (const float*)d_in[0];
    const float* Wqkv  = (const float*)d_in[1];
    const float* Wout  = (const float*)d_in[2];
    // d_in[3] = b_out: cancels exactly under BatchNorm mean subtraction.
    const float* gamma = (const float*)d_in[4];
    const float* beta  = (const float*)d_in[5];

    char* wsb = (char*)d_ws;
    const size_t PANEL = (size_t)ROWS * DPAD * sizeof(unsigned short);  // 8 MB
    unsigned short* xf = (unsigned short*)(wsb);        // fragment-ordered
    unsigned short* yh = (unsigned short*)(wsb + PANEL);
    float*          wv = (float*)(wsb + 2 * PANEL);                     // 256 KB
    unsigned*     Mtpk = (unsigned*)(wsb + 2 * PANEL + 262144);         // 16 KB
    float*           u = (float*)(wsb + 2 * PANEL + 262144 + 16384);
    float*       partL = (float*)(wsb + 2 * PANEL + 262144 + 17408);
    float*       partA = partL + (size_t)SPLIT * BB * FF;
    // total ~= 18.3 MiB

    prep_kernel<<<dim3(17), dim3(256), 0, stream>>>(Wqkv, Wout, Mtpk, u);

    xy_kernel<<<dim3(ROWS / 64), dim3(128), 0, stream>>>(
        x, u, Mtpk, xf, yh, wv);

    attn_kernel<<<dim3(BB * 16 * SPLIT), dim3(256), 0, stream>>>(
        xf, yh, wv, partL, partA);

    bn_kernel<<<dim3(FF / 64), dim3(64), 0, stream>>>(
        partL, partA, gamma, beta, (float*)d_out);
}